// Round 8
// baseline (216.899 us; speedup 1.0000x reference)
//
#include <hip/hip_runtime.h>

typedef __bf16 bf16;
typedef __bf16 bf16x8 __attribute__((ext_vector_type(8)));
typedef __bf16 bf16x4 __attribute__((ext_vector_type(4)));
typedef float  f32x4  __attribute__((ext_vector_type(4)));

#define MFMA_BF16(a, b, c) __builtin_amdgcn_mfma_f32_16x16x32_bf16((a), (b), (c), 0, 0, 0)

// Problem constants: B=2, L=2048, E=1024, H=16, D=64; M=B*L=4096, K=N=E=1024.

__device__ __forceinline__ void async_load16(const bf16* g, const bf16* l) {
    auto gp = (const __attribute__((address_space(1))) unsigned int*)(unsigned long long)(const void*)g;
    auto lp = (__attribute__((address_space(3))) unsigned int*)(unsigned int)(unsigned long long)(const void*)l;
    __builtin_amdgcn_global_load_lds(gp, lp, 16, 0, 0);
}

// ---------------------------------------------------------------------------
// fp32 -> bf16 conversion. Flat 1D grid (16384 blocks), 4 elems/thread.
__global__ void cvt_bf16_kernel(
    const float* __restrict__ s0, const float* __restrict__ s1, const float* __restrict__ s2,
    const float* __restrict__ s3, const float* __restrict__ s4, const float* __restrict__ s5,
    const float* __restrict__ s6,
    bf16* __restrict__ d0, bf16* __restrict__ d1, bf16* __restrict__ d2,
    bf16* __restrict__ d3, bf16* __restrict__ d4, bf16* __restrict__ d5,
    bf16* __restrict__ d6)
{
    unsigned e = (blockIdx.x * 256 + threadIdx.x) * 4;
    const float* src; bf16* dst; unsigned off;
    if (e < 12582912u) {
        unsigned which = e >> 22;
        src = which == 0 ? s0 : (which == 1 ? s1 : s2);
        dst = which == 0 ? d0 : (which == 1 ? d1 : d2);
        off = e & 4194303u;
    } else {
        unsigned ew = e - 12582912u;
        unsigned which = ew >> 20;
        src = which == 0 ? s3 : (which == 1 ? s4 : (which == 2 ? s5 : s6));
        dst = which == 0 ? d3 : (which == 1 ? d4 : (which == 2 ? d5 : d6));
        off = ew & 1048575u;
    }
    float4 f = *(const float4*)(src + off);
    bf16x4 o;
    o.x = (bf16)f.x; o.y = (bf16)f.y; o.z = (bf16)f.z; o.w = (bf16)f.w;
    *(bf16x4*)(dst + off) = o;
}

// ---------------------------------------------------------------------------
// Tiled bf16 GEMM, BM=128 x BN (template), BK=32, 4 waves (2x2).
// BN=128 uses launch_bounds(256,3): 3 blocks/CU so the 768-block projection
// grid is fully resident in ONE round (no half-empty tail round).
//  z=0 (A=Wq, B=Xq): +bq, *0.125*log2e -> Qs [B,H,L,D]
//  z=1 (A=Wk, B=Xk): -> Ksw fragment-major (d lands on j)
//  z=2 (A=Xv, B=Wv): -> Vsw fragment-major (token lands on j)
//  z=3 (A=Wo, B=attn): +bo -> out fp32 (feature-contiguous float4)
template<int BN>
__global__ __launch_bounds__(256, (BN == 128) ? 3 : 4) void gemm4_kernel(
    const bf16* __restrict__ Xq, const bf16* __restrict__ Xk, const bf16* __restrict__ Xv,
    const bf16* __restrict__ Ao,
    const bf16* __restrict__ Wq, const bf16* __restrict__ Wk, const bf16* __restrict__ Wv,
    const bf16* __restrict__ Wo,
    const float* __restrict__ bq, const float* __restrict__ bo,
    bf16* __restrict__ Qs, bf16* __restrict__ Ksw, bf16* __restrict__ Vsw,
    float* __restrict__ out, int zbase)
{
    const int z = zbase + blockIdx.z;
    const bf16 *Amat, *Bmat;
    if (z == 0)      { Amat = Wq; Bmat = Xq; }
    else if (z == 1) { Amat = Wk; Bmat = Xk; }
    else if (z == 2) { Amat = Xv; Bmat = Wv; }
    else             { Amat = Wo; Bmat = Ao; }

    const int m0 = (z == 2 ? blockIdx.y : blockIdx.x) * 128;
    const int n0 = (z == 2 ? blockIdx.x : blockIdx.y) * BN;

    __shared__ __align__(16) bf16 lA[128 * 32];
    __shared__ __align__(16) bf16 lB[BN * 32];

    const int tid  = threadIdx.x;
    const int w    = tid >> 6;
    const int lane = tid & 63;
    const int lm   = lane & 15;
    const int g    = lane >> 4;
    const int wm   = (w & 1) * 64;
    const int wn   = (w >> 1) * (BN / 2);
    constexpr int NT = BN / 32;
    constexpr int T  = (128 + BN) / 64;

    f32x4 acc[4][NT] = {};

    for (int kb = 0; kb < 32; kb++) {
        __syncthreads();
#pragma unroll
        for (int t = 0; t < T; t++) {
            int s   = (t * 4 + w) * 64 + lane;
            int row = s >> 2;
            int gs  = s & 3;
            int gg  = gs ^ ((row >> 1) & 3);
            if (row < 128)
                async_load16(Amat + (size_t)(m0 + row) * 1024 + kb * 32 + gg * 8, lA + s * 8);
            else
                async_load16(Bmat + (size_t)(n0 + row - 128) * 1024 + kb * 32 + gg * 8,
                             lB + (s - 512) * 8);
        }
        __syncthreads();

        bf16x8 af[4], bfr[NT];
#pragma unroll
        for (int mt = 0; mt < 4; mt++) {
            int row = wm + mt * 16 + lm;
            af[mt] = *(const bf16x8*)(lA + row * 32 + ((g ^ ((row >> 1) & 3)) << 3));
        }
#pragma unroll
        for (int nt = 0; nt < NT; nt++) {
            int row = wn + nt * 16 + lm;
            bfr[nt] = *(const bf16x8*)(lB + row * 32 + ((g ^ ((row >> 1) & 3)) << 3));
        }
#pragma unroll
        for (int mt = 0; mt < 4; mt++)
#pragma unroll
            for (int nt = 0; nt < NT; nt++)
                acc[mt][nt] = MFMA_BF16(af[mt], bfr[nt], acc[mt][nt]);
    }

    if (z == 3) {
#pragma unroll
        for (int mt = 0; mt < 4; mt++) {
            int mb = m0 + wm + mt * 16 + g * 4;
            f32x4 bov = *(const f32x4*)(bo + mb);
#pragma unroll
            for (int nt = 0; nt < NT; nt++) {
                int n = n0 + wn + nt * 16 + lm;
                f32x4 val;
#pragma unroll
                for (int r = 0; r < 4; r++) val[r] = acc[mt][nt][r] + bov[r];
                *(f32x4*)(out + (size_t)n * 1024 + mb) = val;
            }
        }
    } else if (z == 2) {
#pragma unroll
        for (int mt = 0; mt < 4; mt++) {
            int mb   = m0 + wm + mt * 16 + g * 4;
            int b    = mb >> 11;
            int lpos = mb & 2047;
            int kb2  = lpos >> 6, kc = (lpos >> 5) & 1, gv = (lpos >> 3) & 3, j0 = lpos & 7;
#pragma unroll
            for (int nt = 0; nt < NT; nt++) {
                int n = n0 + wn + nt * 16 + lm;
                int h = n >> 6, mt2 = (n >> 4) & 3, lmv = n & 15;
                bf16x4 ov;
#pragma unroll
                for (int r = 0; r < 4; r++) ov[r] = (bf16)acc[mt][nt][r];
                *(bf16x4*)(Vsw + (size_t)(b * 16 + h) * 131072 +
                           (size_t)((kb2 * 8 + mt2 * 2 + kc) * 64 + gv * 16 + lmv) * 8 + j0) = ov;
            }
        }
    } else if (z == 1) {
#pragma unroll
        for (int mt = 0; mt < 4; mt++) {
            int mb = m0 + wm + mt * 16 + g * 4;
            int h  = mb >> 6;
            int f  = (mb >> 5) & 1, gk = (mb >> 3) & 3, j0 = mb & 7;
#pragma unroll
            for (int nt = 0; nt < NT; nt++) {
                int n    = n0 + wn + nt * 16 + lm;
                int b    = n >> 11;
                int lpos = n & 2047;
                int kb2  = lpos >> 6;
                int rem  = lpos & 63;
                int c    = ((rem >> 4) & 2) | ((rem >> 2) & 1);
                int lmk  = ((rem >> 1) & 12) | (rem & 3);
                bf16x4 ov;
#pragma unroll
                for (int r = 0; r < 4; r++) ov[r] = (bf16)acc[mt][nt][r];
                *(bf16x4*)(Ksw + (size_t)(b * 16 + h) * 131072 +
                           (size_t)((kb2 * 8 + c * 2 + f) * 64 + gk * 16 + lmk) * 8 + j0) = ov;
            }
        }
    } else {
        const float qscale = 0.18033688011112042f;  // 1/8 * log2(e)
#pragma unroll
        for (int mt = 0; mt < 4; mt++) {
            int mb  = m0 + wm + mt * 16 + g * 4;
            int h   = mb >> 6;
            int dd0 = mb & 63;
            f32x4 bqv = *(const f32x4*)(bq + mb);
#pragma unroll
            for (int nt = 0; nt < NT; nt++) {
                int n    = n0 + wn + nt * 16 + lm;
                int b    = n >> 11;
                int lpos = n & 2047;
                bf16x4 ov;
#pragma unroll
                for (int r = 0; r < 4; r++)
                    ov[r] = (bf16)((acc[mt][nt][r] + bqv[r]) * qscale);
                *(bf16x4*)(Qs + (size_t)((b * 16 + h) * 2048 + lpos) * 64 + dd0) = ov;
            }
        }
    }
}

// ---------------------------------------------------------------------------
// Flash attention (R8 = R6 barrier-free structure, denominator moved to VALU):
// S^T formulation, fragment-major K/V (all loads base + lane*16B), no-max
// softmax p = exp2(s), kb-range split across the block's 2 waves
// (associative combine via LDS at the end). Per iter: 16 S-MFMA + 16 PV-MFMA
// (denominator MFMAs deleted: -11% matrix-pipe work), exp2+pack on VALU,
// K prefetched one stripe ahead, V issued before exp2. No barriers in loop.
__global__ __launch_bounds__(128, 4) void attn_kernel(
    const bf16* __restrict__ Qs, const bf16* __restrict__ Ksw,
    const bf16* __restrict__ Vsw, bf16* __restrict__ attn)
{
    const int w    = threadIdx.x >> 6;   // kb-half owner
    const int lane = threadIdx.x & 63;
    const int lm   = lane & 15;
    const int g    = lane >> 4;
    const int i    = blockIdx.x;
    const int bh   = ((i & 7) << 2) | ((i >> 3) & 3);  // head's 64 blocks -> one XCD
    const int q0   = (i >> 5) * 32;

    const bf16* Qh = Qs  + (size_t)bh * 131072;
    const bf16* kp = Ksw + (size_t)bh * 131072 + (size_t)(w * 16) * 4096 + (size_t)lane * 8;
    const bf16* vp = Vsw + (size_t)bh * 131072 + (size_t)(w * 16) * 4096 + (size_t)lane * 8;

    bf16x8 qf[2][2];
#pragma unroll
    for (int qi = 0; qi < 2; qi++)
#pragma unroll
        for (int f = 0; f < 2; f++)
            qf[qi][f] = *(const bf16x8*)(Qh + (size_t)(q0 + qi * 16 + lm) * 64 + f * 32 + g * 8);

    const f32x4 fzero = {0.0f, 0.0f, 0.0f, 0.0f};
    f32x4 o[2][4] = {};
    float lsum[2] = {0.0f, 0.0f};

    bf16x8 kf[4][2];
#pragma unroll
    for (int c = 0; c < 4; c++)
#pragma unroll
        for (int f = 0; f < 2; f++)
            kf[c][f] = *(const bf16x8*)(kp + (c * 2 + f) * 512);

    for (int kb = 0; kb < 16; kb++) {
        // S^T: s[qi][c][r] = S at k = 32*(c>>1) + 8g + 4*(c&1) + r
        f32x4 s[2][4];
#pragma unroll
        for (int c = 0; c < 4; c++) {
            s[0][c] = MFMA_BF16(kf[c][0], qf[0][0], fzero);
            s[1][c] = MFMA_BF16(kf[c][0], qf[1][0], fzero);
            s[0][c] = MFMA_BF16(kf[c][1], qf[0][1], s[0][c]);
            s[1][c] = MFMA_BF16(kf[c][1], qf[1][1], s[1][c]);
        }

        // V fragments for this stripe; issued so exp2 covers their latency
        bf16x8 vf[4][2];
#pragma unroll
        for (int mt = 0; mt < 4; mt++)
#pragma unroll
            for (int kc = 0; kc < 2; kc++)
                vf[mt][kc] = *(const bf16x8*)(vp + (mt * 2 + kc) * 512);
        vp += 4096;

        // prefetch next K fragments
        kp += 4096;
        if (kb < 15) {
#pragma unroll
            for (int c = 0; c < 4; c++)
#pragma unroll
                for (int f = 0; f < 2; f++)
                    kf[c][f] = *(const bf16x8*)(kp + (c * 2 + f) * 512);
        }

        // p = exp2(s) -> PV B-fragments (k = 32*kc + 8g + j); VALU denominator
        bf16x8 pb[2][2];
#pragma unroll
        for (int qi = 0; qi < 2; qi++) {
            float part = 0.0f;
#pragma unroll
            for (int kc = 0; kc < 2; kc++)
#pragma unroll
                for (int r = 0; r < 4; r++) {
                    float p0 = __builtin_amdgcn_exp2f(s[qi][2 * kc][r]);
                    float p1 = __builtin_amdgcn_exp2f(s[qi][2 * kc + 1][r]);
                    pb[qi][kc][r]     = (bf16)p0;
                    pb[qi][kc][r + 4] = (bf16)p1;
                    part += p0 + p1;
                }
            lsum[qi] += part;
        }

        // O^T += V^T P
#pragma unroll
        for (int kc = 0; kc < 2; kc++)
#pragma unroll
            for (int mt = 0; mt < 4; mt++) {
                o[0][mt] = MFMA_BF16(vf[mt][kc], pb[0][kc], o[0][mt]);
                o[1][mt] = MFMA_BF16(vf[mt][kc], pb[1][kc], o[1][mt]);
            }
    }

    // finish this wave's denominator: reduce across quads
#pragma unroll
    for (int qi = 0; qi < 2; qi++) {
        lsum[qi] += __shfl_xor(lsum[qi], 16);
        lsum[qi] += __shfl_xor(lsum[qi], 32);
    }

    // ---- combine the two kb-halves (associative) ----
    __shared__ float part[64 * 36];
    __shared__ __align__(16) bf16 ost[32 * 72];
    if (w == 1) {
        float* p = part + lane * 36;
#pragma unroll
        for (int qi = 0; qi < 2; qi++)
#pragma unroll
            for (int mt = 0; mt < 4; mt++)
                *(f32x4*)(p + (qi * 4 + mt) * 4) = o[qi][mt];
        p[32] = lsum[0];
        p[33] = lsum[1];
    }
    __syncthreads();
    if (w == 0) {
        const float* p = part + lane * 36;
#pragma unroll
        for (int qi = 0; qi < 2; qi++)
#pragma unroll
            for (int mt = 0; mt < 4; mt++) {
                f32x4 t = *(const f32x4*)(p + (qi * 4 + mt) * 4);
#pragma unroll
                for (int r = 0; r < 4; r++) o[qi][mt][r] += t[r];
            }
        float inv0 = 1.0f / (lsum[0] + p[32]);
        float inv1 = 1.0f / (lsum[1] + p[33]);

        // normalized O -> LDS (row stride 72), then 16B/lane coalesced stores
#pragma unroll
        for (int qi = 0; qi < 2; qi++) {
            float inv = qi ? inv1 : inv0;
#pragma unroll
            for (int mt = 0; mt < 4; mt++) {
                bf16x4 ov;
#pragma unroll
                for (int r = 0; r < 4; r++) ov[r] = (bf16)(o[qi][mt][r] * inv);
                *(bf16x4*)(ost + (qi * 16 + lm) * 72 + mt * 16 + g * 4) = ov;
            }
        }
        const int b = bh >> 4, h = bh & 15;
#pragma unroll
        for (int it = 0; it < 4; it++) {
            int cc = it * 64 + lane;
            int q  = cc >> 3, ch = cc & 7;
            bf16x8 t = *(const bf16x8*)(ost + q * 72 + ch * 8);
            *(bf16x8*)(attn + (size_t)(b * 2048 + q0 + q) * 1024 + h * 64 + ch * 8) = t;
        }
    }
}

// ---------------------------------------------------------------------------
extern "C" void kernel_launch(void* const* d_in, const int* in_sizes, int n_in,
                              void* d_out, int out_size, void* d_ws, size_t ws_size,
                              hipStream_t stream) {
    const float* query = (const float*)d_in[0];
    const float* key   = (const float*)d_in[1];
    const float* value = (const float*)d_in[2];
    const float* Wq    = (const float*)d_in[3];
    const float* bq    = (const float*)d_in[4];
    const float* Wk    = (const float*)d_in[5];
    const float* Wv    = (const float*)d_in[6];
    const float* Wo    = (const float*)d_in[7];
    const float* bo    = (const float*)d_in[8];

    char* ws = (char*)d_ws;
    bf16* Xq  = (bf16*)(ws);
    bf16* Xk  = (bf16*)(ws + ((size_t)8  << 20));
    bf16* Xv  = (bf16*)(ws + ((size_t)16 << 20));
    bf16* Wqb = (bf16*)(ws + ((size_t)24 << 20));
    bf16* Wkb = (bf16*)(ws + ((size_t)26 << 20));
    bf16* Wvb = (bf16*)(ws + ((size_t)28 << 20));
    bf16* Wob = (bf16*)(ws + ((size_t)30 << 20));
    bf16* Qs  = (bf16*)(ws + ((size_t)32 << 20));
    bf16* Ksw = (bf16*)(ws + ((size_t)40 << 20));
    bf16* Vsw = (bf16*)(ws + ((size_t)48 << 20));
    bf16* attn = Xq;  // Xq dead after projections

    cvt_bf16_kernel<<<dim3(16384, 1, 1), 256, 0, stream>>>(
        query, key, value, Wq, Wk, Wv, Wo, Xq, Xk, Xv, Wqb, Wkb, Wvb, Wob);

    gemm4_kernel<128><<<dim3(8, 32, 3), 256, 0, stream>>>(
        Xq, Xk, Xv, attn, Wqb, Wkb, Wvb, Wob, bq, bo, Qs, Ksw, Vsw, (float*)d_out, 0);

    attn_kernel<<<dim3(2048, 1, 1), 128, 0, stream>>>(Qs, Ksw, Vsw, attn);

    gemm4_kernel<64><<<dim3(8, 64, 1), 256, 0, stream>>>(
        Xq, Xk, Xv, attn, Wqb, Wkb, Wvb, Wob, bq, bo, Qs, Ksw, Vsw, (float*)d_out, 3);
}